// Round 1
// baseline (459.112 us; speedup 1.0000x reference)
//
#include <hip/hip_runtime.h>
#include <hip/hip_bf16.h>

#define DEVI static __device__ __forceinline__

using s16x8 = __attribute__((ext_vector_type(8))) short;
using f32x4 = __attribute__((ext_vector_type(4))) float;
using u32x4 = __attribute__((ext_vector_type(4))) unsigned int;

static constexpr int H  = 16;
static constexpr int S  = 1024;
static constexpr int DM = 1024;
static constexpr int NB = 2;          // batch
static constexpr int BS = NB * S;     // 2048
static constexpr long SS  = (long)S * S;
static constexpr long HSS = (long)H * SS;

DEVI unsigned short f2bf(float f) {
    union { float f; unsigned u; } c; c.f = f;
    c.u += 0x7FFFu + ((c.u >> 16) & 1u);   // RNE
    return (unsigned short)(c.u >> 16);
}
DEVI float bf2f(unsigned short v) {
    union { unsigned u; float f; } c; c.u = ((unsigned)v) << 16;
    return c.f;
}

// load 16 contiguous elements, convert to bf16 (ushort)
DEVI void load16(const float* g, unsigned short* v) {
    const float4* g4 = reinterpret_cast<const float4*>(g);
#pragma unroll
    for (int q = 0; q < 4; ++q) {
        float4 x = g4[q];
        v[4*q+0] = f2bf(x.x); v[4*q+1] = f2bf(x.y);
        v[4*q+2] = f2bf(x.z); v[4*q+3] = f2bf(x.w);
    }
}
DEVI void load16(const unsigned short* g, unsigned short* v) {
    const u32x4* g4 = reinterpret_cast<const u32x4*>(g);
    *reinterpret_cast<u32x4*>(v)     = g4[0];
    *reinterpret_cast<u32x4*>(v + 8) = g4[1];
}

enum { EPI_PROJ_BF = 0, EPI_PACK = 1, EPI_MASK = 2, EPI_BF = 3, EPI_F32 = 4, EPI_PROJ_F32 = 5 };

// Unified 64x64-tile MFMA GEMM.
//   out[m][n] = epi( sum_k A[m][k] * B[k][n] )
// A is always row-major [m][k] (global, per-z offset zb*a_sb + zh*a_sh, ld=lda).
// B: if B_KN, global is [k][n] (transposed into LDS); else global is [n][k] (direct).
// CAUSAL_K: limit K-loop to m0+64 (A columns beyond are structurally zero).
// CAUSAL_SKIP: skip (and don't write) blocks with n0 > m0+63.
template<typename TA, typename TB, bool B_KN, int EPI, bool CAUSAL_K, bool CAUSAL_SKIP>
__global__ __launch_bounds__(256)
void gemm64(const TA* __restrict__ Aall, long a_sb, long a_sh, int lda,
            const TB* __restrict__ Ball, long b_sb, long b_sh, int ldb,
            void* __restrict__ Oall, long o_sb, long o_sh, int ldo,
            const float* __restrict__ bias, float alpha, int K)
{
    const int m0 = blockIdx.y * 64;
    const int n0 = blockIdx.x * 64;
    if (CAUSAL_SKIP && n0 > m0 + 63) return;
    const int z  = blockIdx.z;
    const int zb = z / H, zh = z % H;
    const TA* A  = Aall + (long)zb * a_sb + (long)zh * a_sh;
    const TB* Bp = Ball + (long)zb * b_sb + (long)zh * b_sh;

    __shared__ unsigned short lA[64][72];
    __shared__ unsigned short lB[64][72];

    const int tid  = threadIdx.x;
    const int lrow = tid >> 2;          // 0..63
    const int lseg = (tid & 3) << 4;    // 0,16,32,48

    const int wv   = tid >> 6;          // wave 0..3
    const int lane = tid & 63;
    const int wr   = (wv >> 1) << 5;    // wave row offset 0/32
    const int wc   = (wv & 1) << 5;     // wave col offset 0/32
    const int lr   = lane & 15;
    const int lg   = lane >> 4;

    f32x4 acc[2][2] = {};

    int Keff = K;
    if (CAUSAL_K) Keff = min(K, m0 + 64);

    for (int k0 = 0; k0 < Keff; k0 += 64) {
        {   // A tile: rows m0+lrow, cols k0+lseg..+15
            alignas(16) unsigned short tmp[16];
            load16(A + (long)(m0 + lrow) * lda + (k0 + lseg), tmp);
            *reinterpret_cast<u32x4*>(&lA[lrow][lseg])     = *reinterpret_cast<const u32x4*>(tmp);
            *reinterpret_cast<u32x4*>(&lA[lrow][lseg + 8]) = *reinterpret_cast<const u32x4*>(tmp + 8);
        }
        if (!B_KN) {   // B global [n][k] -> direct
            alignas(16) unsigned short tmp[16];
            load16(Bp + (long)(n0 + lrow) * ldb + (k0 + lseg), tmp);
            *reinterpret_cast<u32x4*>(&lB[lrow][lseg])     = *reinterpret_cast<const u32x4*>(tmp);
            *reinterpret_cast<u32x4*>(&lB[lrow][lseg + 8]) = *reinterpret_cast<const u32x4*>(tmp + 8);
        } else {       // B global [k][n] -> transpose into lB[n][k]
            alignas(16) unsigned short tmp[16];
            load16(Bp + (long)(k0 + lrow) * ldb + (n0 + lseg), tmp);
#pragma unroll
            for (int j = 0; j < 16; ++j) lB[lseg + j][lrow] = tmp[j];
        }
        __syncthreads();
#pragma unroll
        for (int kk = 0; kk < 64; kk += 32) {
            s16x8 af[2], bfr[2];
#pragma unroll
            for (int f = 0; f < 2; ++f) {
                af[f]  = *reinterpret_cast<const s16x8*>(&lA[wr + f*16 + lr][kk + 8*lg]);
                bfr[f] = *reinterpret_cast<const s16x8*>(&lB[wc + f*16 + lr][kk + 8*lg]);
            }
#pragma unroll
            for (int fm = 0; fm < 2; ++fm)
#pragma unroll
                for (int fn = 0; fn < 2; ++fn)
                    acc[fm][fn] = __builtin_amdgcn_mfma_f32_16x16x32_bf16(af[fm], bfr[fn], acc[fm][fn], 0, 0, 0);
        }
        __syncthreads();
    }

    const long obase = (long)zb * o_sb + (long)zh * o_sh;
#pragma unroll
    for (int fm = 0; fm < 2; ++fm)
#pragma unroll
        for (int fn = 0; fn < 2; ++fn)
#pragma unroll
            for (int r = 0; r < 4; ++r) {
                const int gm = m0 + wr + fm*16 + lg*4 + r;
                const int gn = n0 + wc + fn*16 + lr;
                float vv = acc[fm][fn][r];
                const long o = obase + (long)gm * ldo + gn;
                if constexpr (EPI == EPI_PROJ_BF) {
                    vv = (vv + bias[gn]) * alpha;
                    ((unsigned short*)Oall)[o] = f2bf(vv);
                } else if constexpr (EPI == EPI_PACK) {
                    vv = vv > 0.f ? vv + 1.f : __expf(vv);   // elu(x)+1
                    ((unsigned short*)Oall)[o] = f2bf(vv);
                } else if constexpr (EPI == EPI_MASK) {
                    vv = (gn <= gm) ? vv / (float)(gm + 1) : 0.f;
                    ((unsigned short*)Oall)[o] = f2bf(vv);
                } else if constexpr (EPI == EPI_BF) {
                    ((unsigned short*)Oall)[o] = f2bf(vv);
                } else if constexpr (EPI == EPI_F32) {
                    ((float*)Oall)[o] = vv;
                } else { // EPI_PROJ_F32
                    ((float*)Oall)[o] = vv + bias[gn];
                }
            }
}

template <typename TI>
__global__ __launch_bounds__(256)
void softmax_rows(const TI* __restrict__ in, unsigned short* __restrict__ out)
{
    const long row = blockIdx.x;
    const int tid = threadIdx.x;
    float v[4];
    if constexpr (sizeof(TI) == 4) {
        float4 x = reinterpret_cast<const float4*>(in + row * S)[tid];
        v[0] = x.x; v[1] = x.y; v[2] = x.z; v[3] = x.w;
    } else {
        ushort4 x = reinterpret_cast<const ushort4*>(in + row * S)[tid];
        v[0] = bf2f(x.x); v[1] = bf2f(x.y); v[2] = bf2f(x.z); v[3] = bf2f(x.w);
    }
    float mx = fmaxf(fmaxf(v[0], v[1]), fmaxf(v[2], v[3]));
#pragma unroll
    for (int off = 32; off; off >>= 1) mx = fmaxf(mx, __shfl_xor(mx, off));
    __shared__ float r1[4], r2[4];
    const int w = tid >> 6, ln = tid & 63;
    if (ln == 0) r1[w] = mx;
    __syncthreads();
    mx = fmaxf(fmaxf(r1[0], r1[1]), fmaxf(r1[2], r1[3]));
    float e[4], s = 0.f;
#pragma unroll
    for (int i = 0; i < 4; ++i) { e[i] = __expf(v[i] - mx); s += e[i]; }
#pragma unroll
    for (int off = 32; off; off >>= 1) s += __shfl_xor(s, off);
    if (ln == 0) r2[w] = s;
    __syncthreads();
    s = r2[0] + r2[1] + r2[2] + r2[3];
    const float inv = 1.f / s;
    ushort4 o;
    o.x = f2bf(e[0]*inv); o.y = f2bf(e[1]*inv); o.z = f2bf(e[2]*inv); o.w = f2bf(e[3]*inv);
    reinterpret_cast<ushort4*>(out + row * S)[tid] = o;
}

__global__ __launch_bounds__(256)
void cast_bf(const float* __restrict__ in, unsigned short* __restrict__ out, int n4)
{
    const int i = blockIdx.x * blockDim.x + threadIdx.x;
    if (i >= n4) return;
    float4 x = reinterpret_cast<const float4*>(in)[i];
    ushort4 o; o.x = f2bf(x.x); o.y = f2bf(x.y); o.z = f2bf(x.z); o.w = f2bf(x.w);
    reinterpret_cast<ushort4*>(out)[i] = o;
}

extern "C" void kernel_launch(void* const* d_in, const int* in_sizes, int n_in,
                              void* d_out, int out_size, void* d_ws, size_t ws_size,
                              hipStream_t stream)
{
    (void)in_sizes; (void)n_in; (void)out_size;
    const float* v_in = (const float*)d_in[0];
    const float* k_in = (const float*)d_in[1];
    const float* q_in = (const float*)d_in[2];
    const float* p_in = (const float*)d_in[3];
    const float* wq   = (const float*)d_in[4];
    const float* wqb  = (const float*)d_in[5];
    const float* wk   = (const float*)d_in[6];
    const float* wkb  = (const float*)d_in[7];
    const float* wvw  = (const float*)d_in[8];
    const float* wvb  = (const float*)d_in[9];
    const float* wc   = (const float*)d_in[10];
    const float* wcb  = (const float*)d_in[11];
    float* out = (float*)d_out;

    char* ws = (char*)d_ws;
    size_t off = 0;
    auto take = [&](size_t n) { char* p = ws + off; off += (n + 255) & ~(size_t)255; return p; };
    unsigned short* qh   = (unsigned short*)take((size_t)BS * DM * 2);
    unsigned short* kh   = (unsigned short*)take((size_t)BS * DM * 2);
    unsigned short* vh   = (unsigned short*)take((size_t)BS * DM * 2);
    unsigned short* ph   = (unsigned short*)take((size_t)BS * DM * 2);
    unsigned short* ao   = (unsigned short*)take((size_t)BS * DM * 2);
    unsigned short* pack = (unsigned short*)take((size_t)NB * HSS * 2);
    unsigned short* W1   = (unsigned short*)take((size_t)NB * HSS * 2);
    const bool f32logits = (ws_size >= off + (size_t)NB * HSS * 4);
    void* W2 = take(f32logits ? (size_t)NB * HSS * 4 : (size_t)NB * HSS * 2);

    const dim3 blk(256);
    const long SDM = (long)S * DM;

    // p -> bf16
    cast_bf<<<dim3(BS * DM / 1024), blk, 0, stream>>>(p_in, ph, BS * DM / 4);

    // projections (f32 in, bf16 out): qh scaled by 1/sqrt(64)
    gemm64<float, float, true, EPI_PROJ_BF, false, false><<<dim3(DM/64, BS/64, 1), blk, 0, stream>>>(
        q_in, 0, 0, DM,  wq, 0, 0, DM,  qh, 0, 0, DM,  wqb, 0.125f, DM);
    gemm64<float, float, true, EPI_PROJ_BF, false, false><<<dim3(DM/64, BS/64, 1), blk, 0, stream>>>(
        k_in, 0, 0, DM,  wk, 0, 0, DM,  kh, 0, 0, DM,  wkb, 1.0f, DM);
    gemm64<float, float, true, EPI_PROJ_BF, false, false><<<dim3(DM/64, BS/64, 1), blk, 0, stream>>>(
        v_in, 0, 0, DM,  wvw, 0, 0, DM, vh, 0, 0, DM,  wvb, 1.0f, DM);

    // pack[t,s] = elu(qh[t]·ph[s]) + 1   (B = ph, [n=s][k=d] direct)
    gemm64<unsigned short, unsigned short, false, EPI_PACK, false, false><<<dim3(S/64, S/64, NB*H), blk, 0, stream>>>(
        qh, SDM, 64, DM,  ph, SDM, 64, DM,  pack, HSS, SS, S,  nullptr, 1.f, 64);

    // sQK[t,s] = (qh[t]·kh[s]) * tril / (t+1)   -> W1
    gemm64<unsigned short, unsigned short, false, EPI_MASK, false, true><<<dim3(S/64, S/64, NB*H), blk, 0, stream>>>(
        qh, SDM, 64, DM,  kh, SDM, 64, DM,  W1, HSS, SS, S,  nullptr, 1.f, 64);

    // unpack[t,j] = sum_s sQK[t,s] * pack[s,j]   (B = pack [k=s][n=j], causal K) -> W2
    if (f32logits)
        gemm64<unsigned short, unsigned short, true, EPI_F32, true, false><<<dim3(S/64, S/64, NB*H), blk, 0, stream>>>(
            W1, HSS, SS, S,  pack, HSS, SS, S,  W2, HSS, SS, S,  nullptr, 1.f, S);
    else
        gemm64<unsigned short, unsigned short, true, EPI_BF, true, false><<<dim3(S/64, S/64, NB*H), blk, 0, stream>>>(
            W1, HSS, SS, S,  pack, HSS, SS, S,  W2, HSS, SS, S,  nullptr, 1.f, S);

    // softmax rows: W2 -> W1 (sm, bf16); W1's sQK contents are dead now
    if (f32logits)
        softmax_rows<float><<<dim3(NB * H * S), blk, 0, stream>>>((const float*)W2, W1);
    else
        softmax_rows<unsigned short><<<dim3(NB * H * S), blk, 0, stream>>>((const unsigned short*)W2, W1);

    // s2[t,s] = (sum_j sm[t,j] pack[s,j]) * tril / (t+1)   (B = pack [n=s][k=j] direct) -> W2 (bf16)
    gemm64<unsigned short, unsigned short, false, EPI_MASK, false, true><<<dim3(S/64, S/64, NB*H), blk, 0, stream>>>(
        W1, HSS, SS, S,  pack, HSS, SS, S,  (unsigned short*)W2, HSS, SS, S,  nullptr, 1.f, S);

    // attn_out[t,d] = sum_s s2[t,s] * vh[s,d]   (B = vh [k=s][n=d], causal K) -> ao
    gemm64<unsigned short, unsigned short, true, EPI_BF, true, false><<<dim3(1, S/64, NB*H), blk, 0, stream>>>(
        (unsigned short*)W2, HSS, SS, S,  vh, SDM, 64, DM,  ao, SDM, 64, DM,  nullptr, 1.f, S);

    // final projection: out = ao @ wc + wcb  (f32 out)
    gemm64<unsigned short, float, true, EPI_PROJ_F32, false, false><<<dim3(DM/64, BS/64, 1), blk, 0, stream>>>(
        ao, 0, 0, DM,  wc, 0, 0, DM,  out, 0, 0, DM,  wcb, 1.f, DM);
}

// Round 2
// 412.431 us; speedup vs baseline: 1.1132x; 1.1132x over previous
//
#include <hip/hip_runtime.h>

#define DEVI static __device__ __forceinline__

using s16x8 = __attribute__((ext_vector_type(8))) short;
using f32x4 = __attribute__((ext_vector_type(4))) float;
using u32x4 = __attribute__((ext_vector_type(4))) unsigned int;

static constexpr int H  = 16;
static constexpr int S  = 1024;
static constexpr int DM = 1024;
static constexpr int NB = 2;          // batch
static constexpr int BS = NB * S;     // 2048
static constexpr long SS  = (long)S * S;
static constexpr long HSS = (long)H * SS;
static constexpr long SDM = (long)S * DM;

DEVI unsigned short f2bf(float f) {
    union { float f; unsigned u; } c; c.f = f;
    c.u += 0x7FFFu + ((c.u >> 16) & 1u);   // RNE
    return (unsigned short)(c.u >> 16);
}
DEVI float bf2f(unsigned short v) {
    union { unsigned u; float f; } c; c.u = ((unsigned)v) << 16;
    return c.f;
}

DEVI void load16(const float* g, unsigned short* v) {
    const float4* g4 = reinterpret_cast<const float4*>(g);
#pragma unroll
    for (int q = 0; q < 4; ++q) {
        float4 x = g4[q];
        v[4*q+0] = f2bf(x.x); v[4*q+1] = f2bf(x.y);
        v[4*q+2] = f2bf(x.z); v[4*q+3] = f2bf(x.w);
    }
}

// async global->LDS, 16 bytes per lane; lds dest = base + lane*16 (wave-linear)
DEVI void gload16(const unsigned short* g, unsigned short* l) {
    __builtin_amdgcn_global_load_lds(
        (const __attribute__((address_space(1))) unsigned int*)g,
        (__attribute__((address_space(3))) unsigned int*)l, 16, 0, 0);
}

enum { EPI_QKPROJ = 0, EPI_VT = 1, EPI_PACK = 2, EPI_MASK = 3, EPI_BF = 4, EPI_F32 = 5, EPI_OUT = 6 };

// 128x128-tile MFMA GEMM, BK=64, 4 waves (each 64x64 = 4x4 16x16x32 frags).
// A: row-major [m][k]; B: row-major [n][k]; per-z offsets zb=z/H, zh=z%H.
// LDS XOR-swizzle (16B-slot ^= row&7) applied via pre-swizzled global source
// (global_load_lds writes linearly) + swizzled ds_read addresses.
// CAUSAL_K: K-loop capped at m0+128.  CAUSAL_SKIP: skip blocks n0 > m0+127.
// NV: valid N (B rows clamped to NV-1, stores guarded gn<NV).
template<int EPI, bool CAUSAL_K, bool CAUSAL_SKIP>
__global__ __launch_bounds__(256)
void gemm128(const unsigned short* __restrict__ Aall, long a_sb, long a_sh, int lda,
             const unsigned short* __restrict__ Ball, long b_sb, long b_sh, int ldb,
             void* __restrict__ Oall, long o_sb, long o_sh, int ldo,
             const float* __restrict__ bias, float alpha, int K, int NV)
{
    const int m0 = blockIdx.y * 128;
    const int n0 = blockIdx.x * 128;
    if (CAUSAL_SKIP && n0 > m0 + 127) return;
    const int z  = blockIdx.z;
    const int zb = z / H, zh = z % H;
    const unsigned short* Ap = Aall + (long)zb * a_sb + (long)zh * a_sh;
    const unsigned short* Bp = Ball + (long)zb * b_sb + (long)zh * b_sh;

    __shared__ unsigned short lA[128 * 64];
    __shared__ unsigned short lB[128 * 64];

    const int tid  = threadIdx.x;
    const int w    = tid >> 6;
    const int lane = tid & 63;
    const int lr   = lane & 15;
    const int lg   = lane >> 4;
    const int wrow = (w >> 1) << 6;   // 0 / 64
    const int wcol = (w & 1) << 6;    // 0 / 64

    // staging pointers: 1024 chunks of 16B per tile, 4 per thread per tile
    const unsigned short* gA[4];
    const unsigned short* gB[4];
    unsigned short* lAp[4];
    unsigned short* lBp[4];
#pragma unroll
    for (int i = 0; i < 4; ++i) {
        const int q = (i*4 + w)*64 + lane;       // 0..1023
        const int row = q >> 3, slot = q & 7;
        const int gslot = slot ^ (row & 7);      // pre-swizzled source slot
        gA[i] = Ap + (long)(m0 + row) * lda + gslot*8;
        int rb = n0 + row; if (rb >= NV) rb = NV - 1;
        gB[i] = Bp + (long)rb * ldb + gslot*8;
        lAp[i] = lA + (i*4 + w)*512;             // wave-uniform base
        lBp[i] = lB + (i*4 + w)*512;
    }

    // ds_read bases (swizzled)
    int abase[4], axor[4], bbase[4], bxor[4];
#pragma unroll
    for (int f = 0; f < 4; ++f) {
        const int ra = wrow + f*16 + lr;
        abase[f] = ra*64; axor[f] = (ra & 7)*8;
        const int rb = wcol + f*16 + lr;
        bbase[f] = rb*64; bxor[f] = (rb & 7)*8;
    }

    f32x4 acc[4][4] = {};
    int Keff = K;
    if (CAUSAL_K) Keff = min(K, m0 + 128);

    for (int k0 = 0; k0 < Keff; k0 += 64) {
#pragma unroll
        for (int i = 0; i < 4; ++i) {
            gload16(gA[i] + k0, lAp[i]);
            gload16(gB[i] + k0, lBp[i]);
        }
        __syncthreads();
#pragma unroll
        for (int kk = 0; kk < 64; kk += 32) {
            s16x8 af[4], bv[4];
#pragma unroll
            for (int f = 0; f < 4; ++f) {
                af[f] = *reinterpret_cast<const s16x8*>(&lA[abase[f] + ((kk + 8*lg) ^ axor[f])]);
                bv[f] = *reinterpret_cast<const s16x8*>(&lB[bbase[f] + ((kk + 8*lg) ^ bxor[f])]);
            }
#pragma unroll
            for (int fm = 0; fm < 4; ++fm)
#pragma unroll
                for (int fn = 0; fn < 4; ++fn)
                    acc[fm][fn] = __builtin_amdgcn_mfma_f32_16x16x32_bf16(af[fm], bv[fn], acc[fm][fn], 0, 0, 0);
        }
        __syncthreads();
    }

    const long obase = (long)zb * o_sb + (long)zh * o_sh;
#pragma unroll
    for (int fm = 0; fm < 4; ++fm)
#pragma unroll
        for (int fn = 0; fn < 4; ++fn)
#pragma unroll
            for (int r = 0; r < 4; ++r) {
                const int gm = m0 + wrow + fm*16 + lg*4 + r;
                const int gn = n0 + wcol + fn*16 + lr;
                if (gn >= NV) continue;
                float vv = acc[fm][fn][r];
                const long o = obase + (long)gm * ldo + gn;
                if constexpr (EPI == EPI_QKPROJ) {
                    ((unsigned short*)Oall)[o] = f2bf((vv + bias[gn]) * alpha);
                } else if constexpr (EPI == EPI_VT) {
                    ((unsigned short*)Oall)[o] = f2bf(vv + bias[gm]);
                } else if constexpr (EPI == EPI_PACK) {
                    vv = vv > 0.f ? vv + 1.f : __expf(vv);   // elu(x)+1
                    ((unsigned short*)Oall)[o] = f2bf(vv);
                } else if constexpr (EPI == EPI_MASK) {
                    vv = (gn <= gm) ? vv / (float)(gm + 1) : 0.f;
                    ((unsigned short*)Oall)[o] = f2bf(vv);
                } else if constexpr (EPI == EPI_BF) {
                    ((unsigned short*)Oall)[o] = f2bf(vv);
                } else if constexpr (EPI == EPI_F32) {
                    ((float*)Oall)[o] = vv;
                } else { // EPI_OUT
                    ((float*)Oall)[o] = vv + bias[gn];
                }
            }
}

template <typename TI>
__global__ __launch_bounds__(256)
void softmax_rows(const TI* __restrict__ in, unsigned short* __restrict__ out)
{
    const long row = blockIdx.x;
    const int tid = threadIdx.x;
    float v[4];
    if constexpr (sizeof(TI) == 4) {
        float4 x = reinterpret_cast<const float4*>(in + row * S)[tid];
        v[0] = x.x; v[1] = x.y; v[2] = x.z; v[3] = x.w;
    } else {
        ushort4 x = reinterpret_cast<const ushort4*>(in + row * S)[tid];
        v[0] = bf2f(x.x); v[1] = bf2f(x.y); v[2] = bf2f(x.z); v[3] = bf2f(x.w);
    }
    float mx = fmaxf(fmaxf(v[0], v[1]), fmaxf(v[2], v[3]));
#pragma unroll
    for (int off = 32; off; off >>= 1) mx = fmaxf(mx, __shfl_xor(mx, off));
    __shared__ float r1[4], r2[4];
    const int w = tid >> 6, ln = tid & 63;
    if (ln == 0) r1[w] = mx;
    __syncthreads();
    mx = fmaxf(fmaxf(r1[0], r1[1]), fmaxf(r1[2], r1[3]));
    float e[4], s = 0.f;
#pragma unroll
    for (int i = 0; i < 4; ++i) { e[i] = __expf(v[i] - mx); s += e[i]; }
#pragma unroll
    for (int off = 32; off; off >>= 1) s += __shfl_xor(s, off);
    if (ln == 0) r2[w] = s;
    __syncthreads();
    s = r2[0] + r2[1] + r2[2] + r2[3];
    const float inv = 1.f / s;
    ushort4 o;
    o.x = f2bf(e[0]*inv); o.y = f2bf(e[1]*inv); o.z = f2bf(e[2]*inv); o.w = f2bf(e[3]*inv);
    reinterpret_cast<ushort4*>(out + row * S)[tid] = o;
}

__global__ __launch_bounds__(256)
void cast_bf(const float* __restrict__ in, unsigned short* __restrict__ out, int n4)
{
    const int i = blockIdx.x * blockDim.x + threadIdx.x;
    if (i >= n4) return;
    float4 x = reinterpret_cast<const float4*>(in)[i];
    ushort4 o; o.x = f2bf(x.x); o.y = f2bf(x.y); o.z = f2bf(x.z); o.w = f2bf(x.w);
    reinterpret_cast<ushort4*>(out)[i] = o;
}

// f32 [n][n] -> bf16 transposed [n][n]
__global__ __launch_bounds__(256)
void twcast(const float* __restrict__ src, unsigned short* __restrict__ dst, int n)
{
    __shared__ unsigned short t[64][72];
    const int r0 = blockIdx.y * 64, c0 = blockIdx.x * 64;
    const int lrow = threadIdx.x >> 2, lseg = (threadIdx.x & 3) << 4;
    alignas(16) unsigned short tmp[16];
    load16(src + (long)(r0 + lrow) * n + c0 + lseg, tmp);
#pragma unroll
    for (int j = 0; j < 16; ++j) t[lrow][lseg + j] = tmp[j];
    __syncthreads();
#pragma unroll
    for (int j = 0; j < 16; ++j) tmp[j] = t[lseg + j][lrow];
    unsigned short* d = dst + (long)(c0 + lrow) * n + r0 + lseg;
    *reinterpret_cast<u32x4*>(d)     = *reinterpret_cast<const u32x4*>(tmp);
    *reinterpret_cast<u32x4*>(d + 8) = *reinterpret_cast<const u32x4*>(tmp + 8);
}

extern "C" void kernel_launch(void* const* d_in, const int* in_sizes, int n_in,
                              void* d_out, int out_size, void* d_ws, size_t ws_size,
                              hipStream_t stream)
{
    (void)in_sizes; (void)n_in; (void)out_size;
    const float* v_in = (const float*)d_in[0];
    const float* k_in = (const float*)d_in[1];
    const float* q_in = (const float*)d_in[2];
    const float* p_in = (const float*)d_in[3];
    const float* wq   = (const float*)d_in[4];
    const float* wqb  = (const float*)d_in[5];
    const float* wk   = (const float*)d_in[6];
    const float* wkb  = (const float*)d_in[7];
    const float* wvw  = (const float*)d_in[8];
    const float* wvb  = (const float*)d_in[9];
    const float* wc   = (const float*)d_in[10];
    const float* wcb  = (const float*)d_in[11];
    float* out = (float*)d_out;

    char* ws = (char*)d_ws;
    size_t off = 0;
    auto take = [&](size_t n) { char* p = ws + off; off += (n + 255) & ~(size_t)255; return p; };
    unsigned short* qbf = (unsigned short*)take((size_t)BS * DM * 2);
    unsigned short* kbf = (unsigned short*)take((size_t)BS * DM * 2);
    unsigned short* vbf = (unsigned short*)take((size_t)BS * DM * 2);
    unsigned short* pbf = (unsigned short*)take((size_t)BS * DM * 2);
    unsigned short* wqT = (unsigned short*)take((size_t)DM * DM * 2);
    unsigned short* wkT = (unsigned short*)take((size_t)DM * DM * 2);
    unsigned short* wvT = (unsigned short*)take((size_t)DM * DM * 2);
    unsigned short* wcT = (unsigned short*)take((size_t)DM * DM * 2);
    unsigned short* qh  = (unsigned short*)take((size_t)BS * DM * 2);
    unsigned short* kh  = (unsigned short*)take((size_t)BS * DM * 2);
    unsigned short* vhT = (unsigned short*)take((size_t)BS * DM * 2);
    unsigned short* ao  = (unsigned short*)take((size_t)BS * DM * 2);
    unsigned short* B1  = (unsigned short*)take((size_t)NB * HSS * 2);
    unsigned short* B2  = (unsigned short*)take((size_t)NB * HSS * 2);
    const bool f32logits = (ws_size >= off + (size_t)NB * HSS * 4);
    void* B3 = take(f32logits ? (size_t)NB * HSS * 4 : (size_t)NB * HSS * 2);

    const dim3 blk(256);

    // f32 -> bf16 casts
    cast_bf<<<dim3(BS*DM/1024), blk, 0, stream>>>(q_in, qbf, BS*DM/4);
    cast_bf<<<dim3(BS*DM/1024), blk, 0, stream>>>(k_in, kbf, BS*DM/4);
    cast_bf<<<dim3(BS*DM/1024), blk, 0, stream>>>(v_in, vbf, BS*DM/4);
    cast_bf<<<dim3(BS*DM/1024), blk, 0, stream>>>(p_in, pbf, BS*DM/4);
    // weight transposes (bf16 [n][k])
    twcast<<<dim3(16,16), blk, 0, stream>>>(wq,  wqT, DM);
    twcast<<<dim3(16,16), blk, 0, stream>>>(wk,  wkT, DM);
    twcast<<<dim3(16,16), blk, 0, stream>>>(wvw, wvT, DM);
    twcast<<<dim3(16,16), blk, 0, stream>>>(wc,  wcT, DM);

    // qh = (q@wq + b) * 1/8 ; kh = k@wk + b
    gemm128<EPI_QKPROJ,false,false><<<dim3(DM/128, BS/128, 1), blk, 0, stream>>>(
        qbf,0,0,DM,  wqT,0,0,DM,  qh,0,0,DM,  wqb, 0.125f, DM, DM);
    gemm128<EPI_QKPROJ,false,false><<<dim3(DM/128, BS/128, 1), blk, 0, stream>>>(
        kbf,0,0,DM,  wkT,0,0,DM,  kh,0,0,DM,  wkb, 1.0f, DM, DM);
    // vhT[b][dm][t] = (v@wv + b)^T : A=wvT [dm][k], B=v [t][k]
    gemm128<EPI_VT,false,false><<<dim3(S/128, DM/128, NB), blk, 0, stream>>>(
        wvT,0,0,DM,  vbf,0,SDM,DM,  vhT,0,(long)DM*S,S,  wvb, 1.0f, DM, S);

    // packT[s][t] = elu(ph[s].qh[t]) + 1  -> B1
    gemm128<EPI_PACK,false,false><<<dim3(8,8,NB*H), blk, 0, stream>>>(
        pbf,SDM,64,DM,  qh,SDM,64,DM,  B1,HSS,SS,S,  nullptr, 1.f, 64, S);
    // sQK[t][s] = (qh.kh) * tril/(t+1)  -> B2
    gemm128<EPI_MASK,false,true><<<dim3(8,8,NB*H), blk, 0, stream>>>(
        qh,SDM,64,DM,  kh,SDM,64,DM,  B2,HSS,SS,S,  nullptr, 1.f, 64, S);
    // unpack = sQK @ pack = B2 @ B1(packT as [n=j][k=s])  -> B3 (logits)
    if (f32logits)
        gemm128<EPI_F32,true,false><<<dim3(8,8,NB*H), blk, 0, stream>>>(
            B2,HSS,SS,S,  B1,HSS,SS,S,  B3,HSS,SS,S,  nullptr, 1.f, S, S);
    else
        gemm128<EPI_BF,true,false><<<dim3(8,8,NB*H), blk, 0, stream>>>(
            B2,HSS,SS,S,  B1,HSS,SS,S,  B3,HSS,SS,S,  nullptr, 1.f, S, S);
    // softmax: B3 -> B2 (sQK dead)
    if (f32logits)
        softmax_rows<float><<<dim3(NB*H*S), blk, 0, stream>>>((const float*)B3, B2);
    else
        softmax_rows<unsigned short><<<dim3(NB*H*S), blk, 0, stream>>>((const unsigned short*)B3, B2);
    // pack[t][s] = elu(qh.ph)+1 -> B1 (packT dead)
    gemm128<EPI_PACK,false,false><<<dim3(8,8,NB*H), blk, 0, stream>>>(
        qh,SDM,64,DM,  pbf,SDM,64,DM,  B1,HSS,SS,S,  nullptr, 1.f, 64, S);
    // s2[t][s] = (sm . pack[s]) * tril/(t+1) : A=B2, B=B1 [n=s][k=j] -> B3 (logits dead)
    gemm128<EPI_MASK,false,true><<<dim3(8,8,NB*H), blk, 0, stream>>>(
        B2,HSS,SS,S,  B1,HSS,SS,S,  (unsigned short*)B3,HSS,SS,S,  nullptr, 1.f, S, S);
    // attn_out[t][d] = s2 @ vh : B = vhT slice [n=d][k=s], N=64 -> ao
    gemm128<EPI_BF,true,false><<<dim3(1, S/128, NB*H), blk, 0, stream>>>(
        (unsigned short*)B3,HSS,SS,S,  vhT,(long)DM*S,(long)64*S,S,  ao,SDM,64,DM,  nullptr, 1.f, S, 64);
    // out = ao @ wc + b (f32)
    gemm128<EPI_OUT,false,false><<<dim3(DM/128, BS/128, 1), blk, 0, stream>>>(
        ao,0,0,DM,  wcT,0,0,DM,  out,0,0,DM,  wcb, 1.f, DM, DM);
}

// Round 3
// 389.917 us; speedup vs baseline: 1.1775x; 1.0577x over previous
//
#include <hip/hip_runtime.h>

#define DEVI static __device__ __forceinline__

using s16x8 = __attribute__((ext_vector_type(8))) short;
using f32x4 = __attribute__((ext_vector_type(4))) float;
using u32x4 = __attribute__((ext_vector_type(4))) unsigned int;

static constexpr int H  = 16;
static constexpr int S  = 1024;
static constexpr int DM = 1024;
static constexpr int NB = 2;          // batch
static constexpr int BS = NB * S;     // 2048
static constexpr long SS  = (long)S * S;
static constexpr long HSS = (long)H * SS;
static constexpr long SDM = (long)S * DM;

DEVI unsigned short f2bf(float f) {
    union { float f; unsigned u; } c; c.f = f;
    c.u += 0x7FFFu + ((c.u >> 16) & 1u);   // RNE
    return (unsigned short)(c.u >> 16);
}
DEVI float bf2f(unsigned short v) {
    union { unsigned u; float f; } c; c.u = ((unsigned)v) << 16;
    return c.f;
}

DEVI void load16(const float* g, unsigned short* v) {
    const float4* g4 = reinterpret_cast<const float4*>(g);
#pragma unroll
    for (int q = 0; q < 4; ++q) {
        float4 x = g4[q];
        v[4*q+0] = f2bf(x.x); v[4*q+1] = f2bf(x.y);
        v[4*q+2] = f2bf(x.z); v[4*q+3] = f2bf(x.w);
    }
}

// async global->LDS, 16 bytes per lane; lds dest = wave-uniform base + lane*16
DEVI void gload16(const unsigned short* g, unsigned short* l) {
    __builtin_amdgcn_global_load_lds(
        (const __attribute__((address_space(1))) unsigned int*)g,
        (__attribute__((address_space(3))) unsigned int*)l, 16, 0, 0);
}

enum { EPI_BFB = 0, EPI_VTB = 1, EPI_PACK = 2, EPI_MASK = 3, EPI_BF = 4, EPI_F32 = 5, EPI_OUT = 6 };

// Tiled MFMA GEMM, TMxTN tile, BK=64, (TM/64)*(TN/64) waves, each wave 64x64
// (4x4 frags of mfma_f32_16x16x32_bf16). Double-buffered LDS, issue-early
// staging (T3 minimum-2-phase), XOR-swizzled LDS via pre-swizzled global src.
// A row-major [m][k]; B row-major [n][k]; out[m][n] = epi(A.B^T).
// z -> (zb=z>>4, zh=z&15) offsets. CK: K capped at m0+TM. CS: skip n0>m0+TM-1.
// REVY: reverse y so longest-K blocks dispatch first.
template<int TM, int TN, int EPI, bool CK, bool CS, bool REVY>
__global__ __launch_bounds__((TM/64)*(TN/64)*64)
void gemmT(const unsigned short* __restrict__ Aall, long a_sb, long a_sh, int lda,
           const unsigned short* __restrict__ Ball, long b_sb, long b_sh, int ldb,
           void* __restrict__ Oall, long o_sb, long o_sh, int ldo,
           const float* __restrict__ bias, int bstride, int K, int NV)
{
    constexpr int WN = TN / 64, WM = TM / 64, NWV = WM * WN, NTHR = NWV * 64;
    constexpr int IA = (TM * 8) / NTHR, IB = (TN * 8) / NTHR;

    const int by = REVY ? ((int)gridDim.y - 1 - (int)blockIdx.y) : (int)blockIdx.y;
    const int m0 = by * TM;
    const int n0 = blockIdx.x * TN;
    if (CS && n0 > m0 + TM - 1) return;
    const int z  = blockIdx.z;
    const int zb = z >> 4, zh = z & 15;
    const unsigned short* Ap = Aall + (long)zb * a_sb + (long)zh * a_sh;
    const unsigned short* Bp = Ball + (long)zb * b_sb + (long)zh * b_sh;
    const float* bi = bias + (long)zh * bstride;   // only deref'd by bias EPIs

    __shared__ alignas(16) unsigned short lA[2][TM * 64];
    __shared__ alignas(16) unsigned short lB[2][TN * 64];

    const int tid = threadIdx.x, w = tid >> 6, lane = tid & 63;
    const int lr = lane & 15, lg = lane >> 4;
    const int wm = (w / WN) * 64, wn = (w % WN) * 64;

    const unsigned short* gA[IA]; int loA[IA];
    const unsigned short* gB[IB]; int loB[IB];
#pragma unroll
    for (int i = 0; i < IA; ++i) {
        const int q = i * NTHR + tid, row = q >> 3, slot = q & 7;
        gA[i]  = Ap + (long)(m0 + row) * lda + ((slot ^ (row & 7)) * 8);
        loA[i] = (i * NWV + w) * 512;             // wave-uniform chunk base
    }
#pragma unroll
    for (int i = 0; i < IB; ++i) {
        const int q = i * NTHR + tid, row = q >> 3, slot = q & 7;
        int rb = n0 + row; if (rb >= NV) rb = NV - 1;
        gB[i]  = Bp + (long)rb * ldb + ((slot ^ (row & 7)) * 8);
        loB[i] = (i * NWV + w) * 512;
    }

    int abase[4], axor[4], bbase[4], bxor[4];
#pragma unroll
    for (int f = 0; f < 4; ++f) {
        const int ra = wm + f * 16 + lr;
        abase[f] = ra * 64; axor[f] = (ra & 7) * 8;
        const int rb = wn + f * 16 + lr;
        bbase[f] = rb * 64; bxor[f] = (rb & 7) * 8;
    }

    f32x4 acc[4][4] = {};
    const int Keff = CK ? min(K, m0 + TM) : K;

    // prologue: stage K-tile 0 into buf 0
#pragma unroll
    for (int i = 0; i < IA; ++i) gload16(gA[i], &lA[0][loA[i]]);
#pragma unroll
    for (int i = 0; i < IB; ++i) gload16(gB[i], &lB[0][loB[i]]);
    __syncthreads();

    int cur = 0;
    for (int k0 = 0; k0 < Keff; k0 += 64) {
        if (k0 + 64 < Keff) {                      // issue-early prefetch
            const int nb = cur ^ 1;
#pragma unroll
            for (int i = 0; i < IA; ++i) gload16(gA[i] + k0 + 64, &lA[nb][loA[i]]);
#pragma unroll
            for (int i = 0; i < IB; ++i) gload16(gB[i] + k0 + 64, &lB[nb][loB[i]]);
        }
#pragma unroll
        for (int kk = 0; kk < 64; kk += 32) {
            s16x8 af[4], bv[4];
#pragma unroll
            for (int f = 0; f < 4; ++f) {
                af[f] = *reinterpret_cast<const s16x8*>(&lA[cur][abase[f] + ((kk + 8 * lg) ^ axor[f])]);
                bv[f] = *reinterpret_cast<const s16x8*>(&lB[cur][bbase[f] + ((kk + 8 * lg) ^ bxor[f])]);
            }
#pragma unroll
            for (int fm = 0; fm < 4; ++fm)
#pragma unroll
                for (int fn = 0; fn < 4; ++fn)
                    acc[fm][fn] = __builtin_amdgcn_mfma_f32_16x16x32_bf16(af[fm], bv[fn], acc[fm][fn], 0, 0, 0);
        }
        __syncthreads();                           // drains vmcnt: prefetch landed
        cur ^= 1;
    }

    const long obase = (long)zb * o_sb + (long)zh * o_sh;
#pragma unroll
    for (int fm = 0; fm < 4; ++fm)
#pragma unroll
        for (int fn = 0; fn < 4; ++fn)
#pragma unroll
            for (int r = 0; r < 4; ++r) {
                const int gm = m0 + wm + fm*16 + lg*4 + r;
                const int gn = n0 + wn + fn*16 + lr;
                if (gn >= NV) continue;
                float vv = acc[fm][fn][r];
                const long o = obase + (long)gm * ldo + gn;
                if constexpr (EPI == EPI_BFB) {
                    ((unsigned short*)Oall)[o] = f2bf(vv + bi[gn]);
                } else if constexpr (EPI == EPI_VTB) {
                    ((unsigned short*)Oall)[o] = f2bf(vv + bi[gm]);
                } else if constexpr (EPI == EPI_PACK) {
                    vv = vv > 0.f ? vv + 1.f : __expf(vv);   // elu(x)+1
                    ((unsigned short*)Oall)[o] = f2bf(vv);
                } else if constexpr (EPI == EPI_MASK) {
                    vv = (gn <= gm) ? vv / (float)(gm + 1) : 0.f;
                    ((unsigned short*)Oall)[o] = f2bf(vv);
                } else if constexpr (EPI == EPI_BF) {
                    ((unsigned short*)Oall)[o] = f2bf(vv);
                } else if constexpr (EPI == EPI_F32) {
                    ((float*)Oall)[o] = vv;
                } else { // EPI_OUT
                    ((float*)Oall)[o] = vv + bi[gn];
                }
            }
}

template <typename TI>
__global__ __launch_bounds__(256)
void softmax_rows(const TI* __restrict__ in, unsigned short* __restrict__ out)
{
    const long row = blockIdx.x;
    const int tid = threadIdx.x;
    float v[4];
    if constexpr (sizeof(TI) == 4) {
        float4 x = reinterpret_cast<const float4*>(in + row * S)[tid];
        v[0] = x.x; v[1] = x.y; v[2] = x.z; v[3] = x.w;
    } else {
        ushort4 x = reinterpret_cast<const ushort4*>(in + row * S)[tid];
        v[0] = bf2f(x.x); v[1] = bf2f(x.y); v[2] = bf2f(x.z); v[3] = bf2f(x.w);
    }
    float mx = fmaxf(fmaxf(v[0], v[1]), fmaxf(v[2], v[3]));
#pragma unroll
    for (int off = 32; off; off >>= 1) mx = fmaxf(mx, __shfl_xor(mx, off));
    __shared__ float r1[4], r2[4];
    const int w = tid >> 6, ln = tid & 63;
    if (ln == 0) r1[w] = mx;
    __syncthreads();
    mx = fmaxf(fmaxf(r1[0], r1[1]), fmaxf(r1[2], r1[3]));
    float e[4], s = 0.f;
#pragma unroll
    for (int i = 0; i < 4; ++i) { e[i] = __expf(v[i] - mx); s += e[i]; }
#pragma unroll
    for (int off = 32; off; off >>= 1) s += __shfl_xor(s, off);
    if (ln == 0) r2[w] = s;
    __syncthreads();
    s = r2[0] + r2[1] + r2[2] + r2[3];
    const float inv = 1.f / s;
    ushort4 o;
    o.x = f2bf(e[0]*inv); o.y = f2bf(e[1]*inv); o.z = f2bf(e[2]*inv); o.w = f2bf(e[3]*inv);
    reinterpret_cast<ushort4*>(out + row * S)[tid] = o;
}

// z selects one of 4 sources; dst contiguous per z
__global__ __launch_bounds__(256)
void cast4(const float* __restrict__ s0, const float* __restrict__ s1,
           const float* __restrict__ s2, const float* __restrict__ s3,
           unsigned short* __restrict__ dst, int n4)
{
    const int i = blockIdx.x * 256 + threadIdx.x;
    if (i >= n4) return;
    const float* s = (blockIdx.z == 0) ? s0 : (blockIdx.z == 1) ? s1 : (blockIdx.z == 2) ? s2 : s3;
    float4 x = reinterpret_cast<const float4*>(s)[i];
    ushort4 o; o.x = f2bf(x.x); o.y = f2bf(x.y); o.z = f2bf(x.z); o.w = f2bf(x.w);
    reinterpret_cast<ushort4*>(dst + (size_t)blockIdx.z * n4 * 4)[i] = o;
}

// f32 [n][n] -> bf16 transposed [n][n], scaled; z selects src, dst contiguous
__global__ __launch_bounds__(256)
void twcast4(const float* __restrict__ s0, const float* __restrict__ s1,
             const float* __restrict__ s2, const float* __restrict__ s3,
             unsigned short* __restrict__ dstall, int n)
{
    __shared__ unsigned short t[64][72];
    const float* src = (blockIdx.z == 0) ? s0 : (blockIdx.z == 1) ? s1 : (blockIdx.z == 2) ? s2 : s3;
    const float scale = (blockIdx.z == 0) ? 0.125f : 1.0f;
    unsigned short* dst = dstall + (size_t)blockIdx.z * n * n;
    const int r0 = blockIdx.y * 64, c0 = blockIdx.x * 64;
    const int lrow = threadIdx.x >> 2, lseg = (threadIdx.x & 3) << 4;
    const float4* g4 = reinterpret_cast<const float4*>(src + (long)(r0 + lrow) * n + c0 + lseg);
    alignas(16) unsigned short tmp[16];
#pragma unroll
    for (int q = 0; q < 4; ++q) {
        float4 x = g4[q];
        tmp[4*q+0] = f2bf(x.x * scale); tmp[4*q+1] = f2bf(x.y * scale);
        tmp[4*q+2] = f2bf(x.z * scale); tmp[4*q+3] = f2bf(x.w * scale);
    }
#pragma unroll
    for (int j = 0; j < 16; ++j) t[lrow][lseg + j] = tmp[j];
    __syncthreads();
#pragma unroll
    for (int j = 0; j < 16; ++j) tmp[j] = t[lseg + j][lrow];
    unsigned short* d = dst + (long)(c0 + lrow) * n + r0 + lseg;
    *reinterpret_cast<u32x4*>(d)     = *reinterpret_cast<const u32x4*>(tmp);
    *reinterpret_cast<u32x4*>(d + 8) = *reinterpret_cast<const u32x4*>(tmp + 8);
}

// bq2[0][:] = wqb * 0.125, bq2[1][:] = wkb
__global__ __launch_bounds__(256)
void bias2(const float* __restrict__ a, const float* __restrict__ b, float* __restrict__ dst)
{
    const int i = blockIdx.x * 256 + threadIdx.x;
    if (i < DM) { dst[i] = a[i] * 0.125f; dst[DM + i] = b[i]; }
}

extern "C" void kernel_launch(void* const* d_in, const int* in_sizes, int n_in,
                              void* d_out, int out_size, void* d_ws, size_t ws_size,
                              hipStream_t stream)
{
    (void)in_sizes; (void)n_in; (void)out_size;
    const float* v_in = (const float*)d_in[0];
    const float* k_in = (const float*)d_in[1];
    const float* q_in = (const float*)d_in[2];
    const float* p_in = (const float*)d_in[3];
    const float* wq   = (const float*)d_in[4];
    const float* wqb  = (const float*)d_in[5];
    const float* wk   = (const float*)d_in[6];
    const float* wkb  = (const float*)d_in[7];
    const float* wvw  = (const float*)d_in[8];
    const float* wvb  = (const float*)d_in[9];
    const float* wc   = (const float*)d_in[10];
    const float* wcb  = (const float*)d_in[11];
    float* out = (float*)d_out;

    char* ws = (char*)d_ws;
    size_t off = 0;
    auto take = [&](size_t n) { char* p = ws + off; off += (n + 255) & ~(size_t)255; return p; };
    unsigned short* qbf = (unsigned short*)take((size_t)BS * DM * 2);  // qbf..pbf contiguous
    unsigned short* kbf = (unsigned short*)take((size_t)BS * DM * 2);
    unsigned short* vbf = (unsigned short*)take((size_t)BS * DM * 2);
    unsigned short* pbf = (unsigned short*)take((size_t)BS * DM * 2);
    unsigned short* wqT = (unsigned short*)take((size_t)DM * DM * 2);  // wqT..wcT contiguous
    unsigned short* wkT = (unsigned short*)take((size_t)DM * DM * 2);
    unsigned short* wvT = (unsigned short*)take((size_t)DM * DM * 2);
    unsigned short* wcT = (unsigned short*)take((size_t)DM * DM * 2);
    float*          bq2 = (float*)take((size_t)2 * DM * 4);
    unsigned short* qh  = (unsigned short*)take((size_t)BS * DM * 2);  // qh,kh contiguous
    unsigned short* kh  = (unsigned short*)take((size_t)BS * DM * 2);
    unsigned short* vhT = (unsigned short*)take((size_t)BS * DM * 2);
    unsigned short* ao  = (unsigned short*)take((size_t)BS * DM * 2);
    unsigned short* B1  = (unsigned short*)take((size_t)NB * HSS * 2);
    unsigned short* B2  = (unsigned short*)take((size_t)NB * HSS * 2);
    const bool f32logits = (ws_size >= off + (size_t)NB * HSS * 4);
    void* B3 = take(f32logits ? (size_t)NB * HSS * 4 : (size_t)NB * HSS * 2);
    (void)kbf; (void)wkT;

    const int n4 = BS * DM / 4;

    // input casts (z: q,k,v,p -> qbf..pbf) ; weight transposes (z: wq*0.125,wk,wv,wc)
    cast4<<<dim3(n4 / 256, 1, 4), dim3(256), 0, stream>>>(q_in, k_in, v_in, p_in, qbf, n4);
    twcast4<<<dim3(16, 16, 4), dim3(256), 0, stream>>>(wq, wk, wvw, wc, wqT, DM);
    bias2<<<dim3(4), dim3(256), 0, stream>>>(wqb, wkb, bq2);

    // q,k projections merged: z in {0,1}: qh/kh = x @ wT + b (alpha folded)
    gemmT<64,128,EPI_BFB,false,false,false><<<dim3(DM/128, BS/64, 2), dim3(128), 0, stream>>>(
        qbf, 0, (long)BS*DM, DM,  wqT, 0, (long)DM*DM, DM,  qh, 0, (long)BS*DM, DM,
        bq2, DM, DM, DM);
    // vhT[b][dm][t] = (v@wv + b)^T : z in {0,1} batches
    gemmT<64,128,EPI_VTB,false,false,false><<<dim3(S/128, DM/64, 2), dim3(128), 0, stream>>>(
        wvT, 0, 0, DM,  vbf, 0, SDM, DM,  vhT, 0, (long)DM*S, S,
        wvb, 0, DM, S);

    // packT[s][t] = elu(ph[s].qh[t]) + 1  -> B1
    gemmT<128,128,EPI_PACK,false,false,false><<<dim3(8, 8, NB*H), dim3(256), 0, stream>>>(
        pbf, SDM, 64, DM,  qh, SDM, 64, DM,  B1, HSS, SS, S,  wvb, 0, 64, S);
    // sQK[t][s] = (qh.kh) * tril/(t+1)  -> B2
    gemmT<128,128,EPI_MASK,false,true,false><<<dim3(8, 8, NB*H), dim3(256), 0, stream>>>(
        qh, SDM, 64, DM,  kh, SDM, 64, DM,  B2, HSS, SS, S,  wvb, 0, 64, S);
    // unpack = sQK @ pack (B = B1 as [j][s])  causal-K, longest-first -> B3
    if (f32logits)
        gemmT<128,128,EPI_F32,true,false,true><<<dim3(8, 8, NB*H), dim3(256), 0, stream>>>(
            B2, HSS, SS, S,  B1, HSS, SS, S,  B3, HSS, SS, S,  wvb, 0, S, S);
    else
        gemmT<128,128,EPI_BF,true,false,true><<<dim3(8, 8, NB*H), dim3(256), 0, stream>>>(
            B2, HSS, SS, S,  B1, HSS, SS, S,  B3, HSS, SS, S,  wvb, 0, S, S);
    // softmax: B3 -> B2 (sQK dead)
    if (f32logits)
        softmax_rows<float><<<dim3(NB*H*S), dim3(256), 0, stream>>>((const float*)B3, B2);
    else
        softmax_rows<unsigned short><<<dim3(NB*H*S), dim3(256), 0, stream>>>((const unsigned short*)B3, B2);
    // pack[t][s] = elu(qh.ph)+1 -> B1 (packT dead)
    gemmT<128,128,EPI_PACK,false,false,false><<<dim3(8, 8, NB*H), dim3(256), 0, stream>>>(
        qh, SDM, 64, DM,  pbf, SDM, 64, DM,  B1, HSS, SS, S,  wvb, 0, 64, S);
    // s2[t][s] = (sm . pack[s]) * tril/(t+1) -> B3 (logits dead), bf16
    gemmT<128,128,EPI_MASK,false,true,false><<<dim3(8, 8, NB*H), dim3(256), 0, stream>>>(
        B2, HSS, SS, S,  B1, HSS, SS, S,  (unsigned short*)B3, HSS, SS, S,  wvb, 0, S, S);
    // attn_out[t][d] = s2 @ vh : B = vhT slice [d][s], TN=64, causal-K longest-first -> ao
    gemmT<128,64,EPI_BF,true,false,true><<<dim3(1, 8, NB*H), dim3(128), 0, stream>>>(
        (unsigned short*)B3, HSS, SS, S,  vhT, (long)DM*S, (long)64*S, S,  ao, SDM, 64, DM,
        wvb, 0, S, 64);
    // out = ao @ wc + b (f32)
    gemmT<64,128,EPI_OUT,false,false,false><<<dim3(DM/128, BS/64, 1), dim3(128), 0, stream>>>(
        ao, 0, 0, DM,  wcT, 0, 0, DM,  out, 0, 0, DM,  wcb, 0, DM, DM);
}

// Round 4
// 387.626 us; speedup vs baseline: 1.1844x; 1.0059x over previous
//
#include <hip/hip_runtime.h>

#define DEVI static __device__ __forceinline__

using s16x8 = __attribute__((ext_vector_type(8))) short;
using f32x4 = __attribute__((ext_vector_type(4))) float;
using u32x4 = __attribute__((ext_vector_type(4))) unsigned int;

static constexpr int H  = 16;
static constexpr int S  = 1024;
static constexpr int DM = 1024;
static constexpr int NB = 2;          // batch
static constexpr int BS = NB * S;     // 2048
static constexpr long SS  = (long)S * S;
static constexpr long HSS = (long)H * SS;
static constexpr long SDM = (long)S * DM;

DEVI unsigned short f2bf(float f) {
    union { float f; unsigned u; } c; c.f = f;
    c.u += 0x7FFFu + ((c.u >> 16) & 1u);   // RNE
    return (unsigned short)(c.u >> 16);
}
DEVI float bf2f(unsigned short v) {
    union { unsigned u; float f; } c; c.u = ((unsigned)v) << 16;
    return c.f;
}

// async global->LDS, 16 bytes per lane; lds dest = wave-uniform base + lane*16
DEVI void gload16(const unsigned short* g, unsigned short* l) {
    __builtin_amdgcn_global_load_lds(
        (const __attribute__((address_space(1))) unsigned int*)g,
        (__attribute__((address_space(3))) unsigned int*)l, 16, 0, 0);
}

enum { EPI_BFB = 0, EPI_VTB, EPI_PACK, EPI_PACK2, EPI_MASK, EPI_BF, EPI_OUT };

// 128x128-tile MFMA GEMM, BK=32, 4-deep pipelined LDS (prefetch distance 3,
// counted vmcnt(8) + raw s_barrier per K-step — T3/T4), 4 waves x (4x4
// mfma_f32_16x16x32_bf16). A row-major [m][k]; B row-major [n][k];
// out[m][n] = epi(A.B^T). XOR-swizzle slot^=(row>>1)&3 on source + read.
// CK: K capped at m0+128. CS: skip n0>m0+127. SWZ: 8x8x32-grid XCD z-group
// remap (same-head blocks -> same XCD, longest-K first). REVY: flip y.
template<int EPI, bool CK, bool CS, bool SWZ, bool REVY>
__global__ __launch_bounds__(256)
void gemmP(const unsigned short* __restrict__ Aall, long a_sb, long a_sh, int lda,
           const unsigned short* __restrict__ Ball, long b_sb, long b_sh, int ldb,
           void* __restrict__ Oall, void* __restrict__ O2, long o_sb, long o_sh, int ldo,
           const float* __restrict__ bias, int bstride, int K, int NV)
{
    int bx, by, bz;
    if (SWZ) {   // grid must be (8,8,32): map linear id so z-group -> one XCD
        const int L = (int)blockIdx.x + ((int)blockIdx.y << 3) + ((int)blockIdx.z << 6);
        const int g = L & 7, r = L >> 3;
        bz = g + ((r >> 6) << 3);
        bx = r & 7;
        by = 7 - ((r >> 3) & 7);                 // longest-K first
    } else {
        bx = blockIdx.x;
        by = REVY ? (int)gridDim.y - 1 - (int)blockIdx.y : (int)blockIdx.y;
        bz = blockIdx.z;
    }
    const int m0 = by * 128, n0 = bx * 128;
    if (CS && n0 > m0 + 127) return;
    const int zb = bz >> 4, zh = bz & 15;
    const unsigned short* Ap = Aall + (long)zb * a_sb + (long)zh * a_sh;
    const unsigned short* Bp = Ball + (long)zb * b_sb + (long)zh * b_sh;
    const float* bi = bias + (long)zh * bstride;

    __shared__ alignas(16) unsigned short lA[4 * 4096];   // 4 stages x 128x32
    __shared__ alignas(16) unsigned short lB[4 * 4096];

    const int tid = threadIdx.x, w = tid >> 6, lane = tid & 63;
    const int lr = lane & 15, lg = lane >> 4;
    const int wm = (w >> 1) << 6, wn = (w & 1) << 6;

    // staging: 512 16B-chunks per 128x32 tile, 2 insts/thread each for A,B
    const unsigned short* gA[2]; const unsigned short* gB[2]; int loA[2];
#pragma unroll
    for (int i = 0; i < 2; ++i) {
        const int q = i * 256 + tid, row = q >> 2, slot = q & 3;
        const int gs = (slot ^ ((row >> 1) & 3)) * 8;     // pre-swizzled source
        gA[i] = Ap + (long)(m0 + row) * lda + gs;
        int rb = n0 + row; if (rb >= NV) rb = NV - 1;
        gB[i] = Bp + (long)rb * ldb + gs;
        loA[i] = (i * 256 + w * 64) * 8;                  // wave-uniform LDS base
    }

    int aoff[4], boff[4];
#pragma unroll
    for (int f = 0; f < 4; ++f) {
        const int Ra = wm + f * 16 + lr;
        aoff[f] = Ra * 32 + 8 * (lg ^ ((Ra >> 1) & 3));   // swizzled read
        const int Rb = wn + f * 16 + lr;
        boff[f] = Rb * 32 + 8 * (lg ^ ((Rb >> 1) & 3));
    }

    f32x4 acc[4][4] = {};
    const int Keff = CK ? ((K < m0 + 128) ? K : m0 + 128) : K;
    const int nt = Keff >> 5;

#define STAGE(BUF, T) do { const long ko_ = (long)(T) << 5;          \
    gload16(gA[0] + ko_, &lA[(BUF) * 4096 + loA[0]]);                 \
    gload16(gA[1] + ko_, &lA[(BUF) * 4096 + loA[1]]);                 \
    gload16(gB[0] + ko_, &lB[(BUF) * 4096 + loA[0]]);                 \
    gload16(gB[1] + ko_, &lB[(BUF) * 4096 + loA[1]]); } while (0)

    // prologue: stage tiles 0..2 (clamped); tile0 must land (keep 8 newest in flight)
    STAGE(0, 0);
    STAGE(1, (1 < nt - 1) ? 1 : nt - 1);
    STAGE(2, (2 < nt - 1) ? 2 : nt - 1);
    asm volatile("s_waitcnt vmcnt(8)" ::: "memory");
    __builtin_amdgcn_s_barrier();

    for (int t = 0; t < nt; ++t) {
        const int tp = (t + 3 < nt) ? t + 3 : nt - 1;     // clamp -> uniform issue
        STAGE((t + 3) & 3, tp);
        const unsigned short* la = &lA[(t & 3) * 4096];
        const unsigned short* lb = &lB[(t & 3) * 4096];
        s16x8 af[4], bv[4];
#pragma unroll
        for (int f = 0; f < 4; ++f) {
            af[f] = *reinterpret_cast<const s16x8*>(&la[aoff[f]]);
            bv[f] = *reinterpret_cast<const s16x8*>(&lb[boff[f]]);
        }
        __builtin_amdgcn_s_setprio(1);
#pragma unroll
        for (int fm = 0; fm < 4; ++fm)
#pragma unroll
            for (int fn = 0; fn < 4; ++fn)
                acc[fm][fn] = __builtin_amdgcn_mfma_f32_16x16x32_bf16(af[fm], bv[fn], acc[fm][fn], 0, 0, 0);
        __builtin_amdgcn_s_setprio(0);
        // keep newest 8 loads (stages t+2,t+3) in flight; stage t+1 forced done
        asm volatile("s_waitcnt vmcnt(8) lgkmcnt(0)" ::: "memory");
        __builtin_amdgcn_s_barrier();
    }
#undef STAGE
    // drain dummy/tail loads before block retires (LDS reallocation hazard)
    asm volatile("s_waitcnt vmcnt(0)" ::: "memory");

    const long obase = (long)zb * o_sb + (long)zh * o_sh;
#pragma unroll
    for (int fm = 0; fm < 4; ++fm)
#pragma unroll
        for (int fn = 0; fn < 4; ++fn) {
            const int t0 = m0 + wm + fm * 16 + lg * 4;
            const int gn = n0 + wn + fn * 16 + lr;
            if (gn >= NV) continue;
            if constexpr (EPI == EPI_PACK2) {             // dual store: P and P^T
                ushort4 pt;
                unsigned short* o1 = (unsigned short*)Oall;
                unsigned short* o2 = (unsigned short*)O2;
#pragma unroll
                for (int r = 0; r < 4; ++r) {
                    float vv = acc[fm][fn][r];
                    vv = vv > 0.f ? vv + 1.f : __expf(vv);   // elu(x)+1
                    const unsigned short b = f2bf(vv);
                    o1[obase + (long)(t0 + r) * ldo + gn] = b;
                    ((unsigned short*)&pt)[r] = b;
                }
                *reinterpret_cast<ushort4*>(&o2[obase + (long)gn * ldo + t0]) = pt;
            } else {
#pragma unroll
                for (int r = 0; r < 4; ++r) {
                    const int gm = t0 + r;
                    float vv = acc[fm][fn][r];
                    const long o = obase + (long)gm * ldo + gn;
                    if constexpr (EPI == EPI_BFB) {
                        ((unsigned short*)Oall)[o] = f2bf(vv + bi[gn]);
                    } else if constexpr (EPI == EPI_VTB) {
                        ((unsigned short*)Oall)[o] = f2bf(vv + bi[gm]);
                    } else if constexpr (EPI == EPI_PACK) {
                        vv = vv > 0.f ? vv + 1.f : __expf(vv);
                        ((unsigned short*)Oall)[o] = f2bf(vv);
                    } else if constexpr (EPI == EPI_MASK) {
                        vv = (gn <= gm) ? vv / (float)(gm + 1) : 0.f;
                        ((unsigned short*)Oall)[o] = f2bf(vv);
                    } else if constexpr (EPI == EPI_BF) {
                        ((unsigned short*)Oall)[o] = f2bf(vv);
                    } else { // EPI_OUT
                        ((float*)Oall)[o] = vv + bi[gn];
                    }
                }
            }
        }
}

__global__ __launch_bounds__(256)
void softmax_rows(const unsigned short* __restrict__ in, unsigned short* __restrict__ out)
{
    const long row = blockIdx.x;
    const int tid = threadIdx.x;
    ushort4 x = reinterpret_cast<const ushort4*>(in + row * S)[tid];
    float v[4] = { bf2f(x.x), bf2f(x.y), bf2f(x.z), bf2f(x.w) };
    float mx = fmaxf(fmaxf(v[0], v[1]), fmaxf(v[2], v[3]));
#pragma unroll
    for (int off = 32; off; off >>= 1) mx = fmaxf(mx, __shfl_xor(mx, off));
    __shared__ float r1[4], r2[4];
    const int w = tid >> 6, ln = tid & 63;
    if (ln == 0) r1[w] = mx;
    __syncthreads();
    mx = fmaxf(fmaxf(r1[0], r1[1]), fmaxf(r1[2], r1[3]));
    float e[4], s = 0.f;
#pragma unroll
    for (int i = 0; i < 4; ++i) { e[i] = __expf(v[i] - mx); s += e[i]; }
#pragma unroll
    for (int off = 32; off; off >>= 1) s += __shfl_xor(s, off);
    if (ln == 0) r2[w] = s;
    __syncthreads();
    s = r2[0] + r2[1] + r2[2] + r2[3];
    const float inv = 1.f / s;
    ushort4 o;
    o.x = f2bf(e[0]*inv); o.y = f2bf(e[1]*inv); o.z = f2bf(e[2]*inv); o.w = f2bf(e[3]*inv);
    reinterpret_cast<ushort4*>(out + row * S)[tid] = o;
}

// z selects one of 4 sources; dst contiguous per z
__global__ __launch_bounds__(256)
void cast4(const float* __restrict__ s0, const float* __restrict__ s1,
           const float* __restrict__ s2, const float* __restrict__ s3,
           unsigned short* __restrict__ dst, int n4)
{
    const int i = blockIdx.x * 256 + threadIdx.x;
    if (i >= n4) return;
    const float* s = (blockIdx.z == 0) ? s0 : (blockIdx.z == 1) ? s1 : (blockIdx.z == 2) ? s2 : s3;
    float4 x = reinterpret_cast<const float4*>(s)[i];
    ushort4 o; o.x = f2bf(x.x); o.y = f2bf(x.y); o.z = f2bf(x.z); o.w = f2bf(x.w);
    reinterpret_cast<ushort4*>(dst + (size_t)blockIdx.z * n4 * 4)[i] = o;
}

// f32 [n][n] -> bf16 transposed [n][n], scaled; z selects src, dst contiguous
__global__ __launch_bounds__(256)
void twcast4(const float* __restrict__ s0, const float* __restrict__ s1,
             const float* __restrict__ s2, const float* __restrict__ s3,
             unsigned short* __restrict__ dstall, int n)
{
    __shared__ unsigned short t[64][72];
    const float* src = (blockIdx.z == 0) ? s0 : (blockIdx.z == 1) ? s1 : (blockIdx.z == 2) ? s2 : s3;
    const float scale = (blockIdx.z == 0) ? 0.125f : 1.0f;
    unsigned short* dst = dstall + (size_t)blockIdx.z * n * n;
    const int r0 = blockIdx.y * 64, c0 = blockIdx.x * 64;
    const int lrow = threadIdx.x >> 2, lseg = (threadIdx.x & 3) << 4;
    const float4* g4 = reinterpret_cast<const float4*>(src + (long)(r0 + lrow) * n + c0 + lseg);
    alignas(16) unsigned short tmp[16];
#pragma unroll
    for (int q = 0; q < 4; ++q) {
        float4 x = g4[q];
        tmp[4*q+0] = f2bf(x.x * scale); tmp[4*q+1] = f2bf(x.y * scale);
        tmp[4*q+2] = f2bf(x.z * scale); tmp[4*q+3] = f2bf(x.w * scale);
    }
#pragma unroll
    for (int j = 0; j < 16; ++j) t[lrow][lseg + j] = tmp[j];
    __syncthreads();
#pragma unroll
    for (int j = 0; j < 16; ++j) tmp[j] = t[lseg + j][lrow];
    unsigned short* d = dst + (long)(c0 + lrow) * n + r0 + lseg;
    *reinterpret_cast<u32x4*>(d)     = *reinterpret_cast<const u32x4*>(tmp);
    *reinterpret_cast<u32x4*>(d + 8) = *reinterpret_cast<const u32x4*>(tmp + 8);
}

// bq2[0][:] = wqb * 0.125, bq2[1][:] = wkb
__global__ __launch_bounds__(256)
void bias2(const float* __restrict__ a, const float* __restrict__ b, float* __restrict__ dst)
{
    const int i = blockIdx.x * 256 + threadIdx.x;
    if (i < DM) { dst[i] = a[i] * 0.125f; dst[DM + i] = b[i]; }
}

extern "C" void kernel_launch(void* const* d_in, const int* in_sizes, int n_in,
                              void* d_out, int out_size, void* d_ws, size_t ws_size,
                              hipStream_t stream)
{
    (void)in_sizes; (void)n_in; (void)out_size;
    const float* v_in = (const float*)d_in[0];
    const float* k_in = (const float*)d_in[1];
    const float* q_in = (const float*)d_in[2];
    const float* p_in = (const float*)d_in[3];
    const float* wq   = (const float*)d_in[4];
    const float* wqb  = (const float*)d_in[5];
    const float* wk   = (const float*)d_in[6];
    const float* wkb  = (const float*)d_in[7];
    const float* wvw  = (const float*)d_in[8];
    const float* wvb  = (const float*)d_in[9];
    const float* wc   = (const float*)d_in[10];
    const float* wcb  = (const float*)d_in[11];
    float* out = (float*)d_out;

    char* ws = (char*)d_ws;
    size_t off = 0;
    auto take = [&](size_t n) { char* p = ws + off; off += (n + 255) & ~(size_t)255; return p; };
    unsigned short* qbf = (unsigned short*)take((size_t)BS * DM * 2);  // qbf..pbf contiguous
    unsigned short* kbf = (unsigned short*)take((size_t)BS * DM * 2);
    unsigned short* vbf = (unsigned short*)take((size_t)BS * DM * 2);
    unsigned short* pbf = (unsigned short*)take((size_t)BS * DM * 2);
    unsigned short* wqT = (unsigned short*)take((size_t)DM * DM * 2);  // wqT..wcT contiguous
    unsigned short* wkT = (unsigned short*)take((size_t)DM * DM * 2);
    unsigned short* wvT = (unsigned short*)take((size_t)DM * DM * 2);
    unsigned short* wcT = (unsigned short*)take((size_t)DM * DM * 2);
    float*          bq2 = (float*)take((size_t)2 * DM * 4);
    unsigned short* qh  = (unsigned short*)take((size_t)BS * DM * 2);  // qh,kh contiguous
    unsigned short* kh  = (unsigned short*)take((size_t)BS * DM * 2);
    unsigned short* vhT = (unsigned short*)take((size_t)BS * DM * 2);
    unsigned short* ao  = (unsigned short*)take((size_t)BS * DM * 2);
    const size_t ssz = (size_t)NB * HSS * 2;
    unsigned short* B1 = (unsigned short*)take(ssz);
    unsigned short* B2 = (unsigned short*)take(ssz);
    unsigned short* B3 = (unsigned short*)take(ssz);
    const bool dual = (ws_size >= off + ssz);          // 4th S x S buffer fits?
    unsigned short* B4 = dual ? (unsigned short*)take(ssz) : nullptr;
    (void)kbf; (void)wkT;

    const int n4 = BS * DM / 4;
    const dim3 blk(256);

    cast4<<<dim3(n4 / 256, 1, 4), blk, 0, stream>>>(q_in, k_in, v_in, p_in, qbf, n4);
    twcast4<<<dim3(16, 16, 4), blk, 0, stream>>>(wq, wk, wvw, wc, wqT, DM);
    bias2<<<dim3(4), blk, 0, stream>>>(wqb, wkb, bq2);

    // q,k projections merged over z (alpha folded into wqT/bq2)
    gemmP<EPI_BFB,false,false,false,false><<<dim3(8, 16, 2), blk, 0, stream>>>(
        qbf, 0, (long)BS*DM, DM,  wqT, 0, (long)DM*DM, DM,  qh, nullptr, 0, (long)BS*DM, DM,
        bq2, DM, DM, DM);
    // vhT[b][dm][t] = (v@wv + b)^T
    gemmP<EPI_VTB,false,false,false,false><<<dim3(8, 8, 2), blk, 0, stream>>>(
        wvT, 0, 0, DM,  vbf, 0, SDM, DM,  vhT, nullptr, 0, (long)DM*S, S,
        wvb, 0, DM, S);

    unsigned short *sqkbuf, *ptbuf, *pbuf = B1, *lbuf;
    if (dual) {
        // P -> B1, P^T -> B2 in one pass
        gemmP<EPI_PACK2,false,false,true,false><<<dim3(8, 8, 32), blk, 0, stream>>>(
            qh, SDM, 64, DM,  pbf, SDM, 64, DM,  B1, B2, HSS, SS, S,  wvb, 0, 64, S);
        ptbuf = B2; sqkbuf = B3; lbuf = B4;
    } else {
        // packT[s][t] = elu(ph[s].qh[t])+1 -> B1
        gemmP<EPI_PACK,false,false,true,false><<<dim3(8, 8, 32), blk, 0, stream>>>(
            pbf, SDM, 64, DM,  qh, SDM, 64, DM,  B1, nullptr, HSS, SS, S,  wvb, 0, 64, S);
        ptbuf = B1; sqkbuf = B2; lbuf = B3;
    }
    // sQK[t][s] = (qh.kh) * tril/(t+1)
    gemmP<EPI_MASK,false,true,true,false><<<dim3(8, 8, 32), blk, 0, stream>>>(
        qh, SDM, 64, DM,  kh, SDM, 64, DM,  sqkbuf, nullptr, HSS, SS, S,  wvb, 0, 64, S);
    // unpack (logits) = sQK @ P  (B = P^T rows j), causal-K -> lbuf (bf16)
    gemmP<EPI_BF,true,false,true,false><<<dim3(8, 8, 32), blk, 0, stream>>>(
        sqkbuf, HSS, SS, S,  ptbuf, HSS, SS, S,  lbuf, nullptr, HSS, SS, S,  wvb, 0, S, S);
    // softmax: lbuf -> sqkbuf (sQK dead)
    softmax_rows<<<dim3(NB*H*S), blk, 0, stream>>>(lbuf, sqkbuf);
    if (!dual) {
        // pack[t][s] = elu(qh.ph)+1 -> B1 (packT dead)
        gemmP<EPI_PACK,false,false,true,false><<<dim3(8, 8, 32), blk, 0, stream>>>(
            qh, SDM, 64, DM,  pbf, SDM, 64, DM,  B1, nullptr, HSS, SS, S,  wvb, 0, 64, S);
    }
    // s2[t][s] = (sm . P[s,:]) * tril/(t+1)  (B = P rows s, K = S full) -> lbuf (logits dead)
    gemmP<EPI_MASK,false,true,true,false><<<dim3(8, 8, 32), blk, 0, stream>>>(
        sqkbuf, HSS, SS, S,  pbuf, HSS, SS, S,  lbuf, nullptr, HSS, SS, S,  wvb, 0, S, S);
    // attn_out[t][d] = s2 @ vh (B = vhT head-slice [d][s], NV=64), causal-K
    gemmP<EPI_BF,true,false,false,true><<<dim3(1, 8, 32), blk, 0, stream>>>(
        lbuf, HSS, SS, S,  vhT, (long)DM*S, (long)64*S, S,  ao, nullptr, SDM, 64, DM,
        wvb, 0, S, 64);
    // out = ao @ wc + b (f32)
    gemmP<EPI_OUT,false,false,false,false><<<dim3(8, 16, 1), blk, 0, stream>>>(
        ao, 0, 0, DM,  wcT, 0, 0, DM,  out, nullptr, 0, 0, DM,  wcb, 0, DM, DM);
}

// Round 5
// 308.684 us; speedup vs baseline: 1.4873x; 1.2557x over previous
//
#include <hip/hip_runtime.h>

#define DEVI static __device__ __forceinline__

using s16x8 = __attribute__((ext_vector_type(8))) short;
using f32x4 = __attribute__((ext_vector_type(4))) float;
using u32x4 = __attribute__((ext_vector_type(4))) unsigned int;

static constexpr int H  = 16;
static constexpr int S  = 1024;
static constexpr int DM = 1024;
static constexpr int NB = 2;          // batch
static constexpr int BS = NB * S;     // 2048
static constexpr long SS  = (long)S * S;
static constexpr long HSS = (long)H * SS;
static constexpr long SDM = (long)S * DM;

DEVI unsigned short f2bf(float f) {
    union { float f; unsigned u; } c; c.f = f;
    c.u += 0x7FFFu + ((c.u >> 16) & 1u);   // RNE
    return (unsigned short)(c.u >> 16);
}
DEVI float bf2f(unsigned short v) {
    union { unsigned u; float f; } c; c.u = ((unsigned)v) << 16;
    return c.f;
}

// async global->LDS, 16 bytes per lane; lds dest = wave-uniform base + lane*16
DEVI void gload16(const unsigned short* g, unsigned short* l) {
    __builtin_amdgcn_global_load_lds(
        (const __attribute__((address_space(1))) unsigned int*)g,
        (__attribute__((address_space(3))) unsigned int*)l, 16, 0, 0);
}

enum { EPI_BFB = 0, EPI_VTB, EPI_PACK, EPI_PACK2, EPI_MASK, EPI_BF, EPI_OUT };

// 128x128-tile MFMA GEMM, BK=64, SINGLE 32KB LDS buffer (m97 structure:
// stage -> syncthreads -> 32 MFMA/wave -> syncthreads; latency hidden by
// ~5 co-resident blocks/CU). 4 waves x (4x4 mfma_f32_16x16x32_bf16).
// A row-major [m][k]; B row-major [n][k]; out[m][n] = epi(A.B^T).
// XOR-swizzle slot^=(row&7) on pre-swizzled global source + swizzled read.
// CK: K capped at m0+128. CS: skip n0>m0+127. SWZ: (8,8,32)-grid XCD z-group
// remap (same-head blocks -> one XCD, longest-K first). REVY: flip y.
template<int EPI, bool CK, bool CS, bool SWZ, bool REVY>
__global__ __launch_bounds__(256)
void gemmS(const unsigned short* __restrict__ Aall, long a_sb, long a_sh, int lda,
           const unsigned short* __restrict__ Ball, long b_sb, long b_sh, int ldb,
           void* __restrict__ Oall, void* __restrict__ O2, long o_sb, long o_sh, int ldo,
           const float* __restrict__ bias, int bstride, int K, int NV)
{
    int bx, by, bz;
    if (SWZ) {   // grid must be (8,8,32)
        const int L = (int)blockIdx.x + ((int)blockIdx.y << 3) + ((int)blockIdx.z << 6);
        const int g = L & 7, r = L >> 3;
        bz = g + ((r >> 6) << 3);
        bx = r & 7;
        by = 7 - ((r >> 3) & 7);                 // longest-K first
    } else {
        bx = blockIdx.x;
        by = REVY ? (int)gridDim.y - 1 - (int)blockIdx.y : (int)blockIdx.y;
        bz = blockIdx.z;
    }
    const int m0 = by * 128, n0 = bx * 128;
    if (CS && n0 > m0 + 127) return;
    const int zb = bz >> 4, zh = bz & 15;
    const unsigned short* Ap = Aall + (long)zb * a_sb + (long)zh * a_sh;
    const unsigned short* Bp = Ball + (long)zb * b_sb + (long)zh * b_sh;
    const float* bi = bias + (long)zh * bstride;

    __shared__ alignas(16) unsigned short lA[128 * 64];   // 16 KB
    __shared__ alignas(16) unsigned short lB[128 * 64];   // 16 KB

    const int tid = threadIdx.x, w = tid >> 6, lane = tid & 63;
    const int lr = lane & 15, lg = lane >> 4;
    const int wm = (w >> 1) << 6, wn = (w & 1) << 6;

    // staging: 1024 16B-chunks per 128x64 tile, 4 insts/thread each for A,B
    const unsigned short* gA[4]; const unsigned short* gB[4]; int lo[4];
#pragma unroll
    for (int i = 0; i < 4; ++i) {
        const int q = (i * 4 + w) * 64 + lane, row = q >> 3, slot = q & 7;
        const int gs = (slot ^ (row & 7)) * 8;            // pre-swizzled source
        gA[i] = Ap + (long)(m0 + row) * lda + gs;
        int rb = n0 + row; if (rb >= NV) rb = NV - 1;
        gB[i] = Bp + (long)rb * ldb + gs;
        lo[i] = (i * 4 + w) * 512;                        // wave-uniform LDS base
    }

    int abase[4], axor[4], bbase[4], bxor[4];
#pragma unroll
    for (int f = 0; f < 4; ++f) {
        const int ra = wm + f * 16 + lr;
        abase[f] = ra * 64; axor[f] = (ra & 7) * 8;       // swizzled read
        const int rb = wn + f * 16 + lr;
        bbase[f] = rb * 64; bxor[f] = (rb & 7) * 8;
    }

    f32x4 acc[4][4] = {};
    const int Keff = CK ? ((K < m0 + 128) ? K : m0 + 128) : K;

    for (int k0 = 0; k0 < Keff; k0 += 64) {
#pragma unroll
        for (int i = 0; i < 4; ++i) {
            gload16(gA[i] + k0, &lA[lo[i]]);
            gload16(gB[i] + k0, &lB[lo[i]]);
        }
        __syncthreads();                                  // drains vmcnt(0)
#pragma unroll
        for (int kk = 0; kk < 64; kk += 32) {
            s16x8 af[4], bv[4];
#pragma unroll
            for (int f = 0; f < 4; ++f) {
                af[f] = *reinterpret_cast<const s16x8*>(&lA[abase[f] + ((kk + 8 * lg) ^ axor[f])]);
                bv[f] = *reinterpret_cast<const s16x8*>(&lB[bbase[f] + ((kk + 8 * lg) ^ bxor[f])]);
            }
#pragma unroll
            for (int fm = 0; fm < 4; ++fm)
#pragma unroll
                for (int fn = 0; fn < 4; ++fn)
                    acc[fm][fn] = __builtin_amdgcn_mfma_f32_16x16x32_bf16(af[fm], bv[fn], acc[fm][fn], 0, 0, 0);
        }
        __syncthreads();
    }

    const long obase = (long)zb * o_sb + (long)zh * o_sh;
#pragma unroll
    for (int fm = 0; fm < 4; ++fm)
#pragma unroll
        for (int fn = 0; fn < 4; ++fn) {
            const int t0 = m0 + wm + fm * 16 + lg * 4;
            const int gn = n0 + wn + fn * 16 + lr;
            if (gn >= NV) continue;
            if constexpr (EPI == EPI_PACK2) {             // dual store: P and P^T
                ushort4 pt;
                unsigned short* o1 = (unsigned short*)Oall;
                unsigned short* o2 = (unsigned short*)O2;
#pragma unroll
                for (int r = 0; r < 4; ++r) {
                    float vv = acc[fm][fn][r];
                    vv = vv > 0.f ? vv + 1.f : __expf(vv);   // elu(x)+1
                    const unsigned short b = f2bf(vv);
                    o1[obase + (long)(t0 + r) * ldo + gn] = b;
                    ((unsigned short*)&pt)[r] = b;
                }
                *reinterpret_cast<ushort4*>(&o2[obase + (long)gn * ldo + t0]) = pt;
            } else {
#pragma unroll
                for (int r = 0; r < 4; ++r) {
                    const int gm = t0 + r;
                    float vv = acc[fm][fn][r];
                    const long o = obase + (long)gm * ldo + gn;
                    if constexpr (EPI == EPI_BFB) {
                        ((unsigned short*)Oall)[o] = f2bf(vv + bi[gn]);
                    } else if constexpr (EPI == EPI_VTB) {
                        ((unsigned short*)Oall)[o] = f2bf(vv + bi[gm]);
                    } else if constexpr (EPI == EPI_PACK) {
                        vv = vv > 0.f ? vv + 1.f : __expf(vv);
                        ((unsigned short*)Oall)[o] = f2bf(vv);
                    } else if constexpr (EPI == EPI_MASK) {
                        vv = (gn <= gm) ? vv / (float)(gm + 1) : 0.f;
                        ((unsigned short*)Oall)[o] = f2bf(vv);
                    } else if constexpr (EPI == EPI_BF) {
                        ((unsigned short*)Oall)[o] = f2bf(vv);
                    } else { // EPI_OUT
                        ((float*)Oall)[o] = vv + bi[gn];
                    }
                }
            }
        }
}

// wave-per-row softmax: 4 rows/block, no cross-wave sync; 32 B/lane loads
__global__ __launch_bounds__(256)
void softmax_rows(const unsigned short* __restrict__ in, unsigned short* __restrict__ out)
{
    const int w = threadIdx.x >> 6, lane = threadIdx.x & 63;
    const long row = (long)blockIdx.x * 4 + w;
    const u32x4* r4 = reinterpret_cast<const u32x4*>(in + row * S);
    u32x4 a = r4[lane * 2], b = r4[lane * 2 + 1];
    float v[16];
#pragma unroll
    for (int i = 0; i < 4; ++i) {
        v[2*i]     = bf2f((unsigned short)(a[i] & 0xFFFF));
        v[2*i+1]   = bf2f((unsigned short)(a[i] >> 16));
        v[8+2*i]   = bf2f((unsigned short)(b[i] & 0xFFFF));
        v[8+2*i+1] = bf2f((unsigned short)(b[i] >> 16));
    }
    float mx = v[0];
#pragma unroll
    for (int i = 1; i < 16; ++i) mx = fmaxf(mx, v[i]);
#pragma unroll
    for (int off = 32; off; off >>= 1) mx = fmaxf(mx, __shfl_xor(mx, off));
    float e[16], s = 0.f;
#pragma unroll
    for (int i = 0; i < 16; ++i) { e[i] = __expf(v[i] - mx); s += e[i]; }
#pragma unroll
    for (int off = 32; off; off >>= 1) s += __shfl_xor(s, off);
    const float inv = 1.f / s;
    u32x4 oa, ob;
#pragma unroll
    for (int i = 0; i < 4; ++i) {
        oa[i] = (unsigned)f2bf(e[2*i]   * inv) | ((unsigned)f2bf(e[2*i+1]   * inv) << 16);
        ob[i] = (unsigned)f2bf(e[8+2*i] * inv) | ((unsigned)f2bf(e[8+2*i+1] * inv) << 16);
    }
    u32x4* o4 = reinterpret_cast<u32x4*>(out + row * S);
    o4[lane * 2] = oa; o4[lane * 2 + 1] = ob;
}

// z selects one of 4 sources; dst contiguous per z
__global__ __launch_bounds__(256)
void cast4(const float* __restrict__ s0, const float* __restrict__ s1,
           const float* __restrict__ s2, const float* __restrict__ s3,
           unsigned short* __restrict__ dst, int n4)
{
    const int i = blockIdx.x * 256 + threadIdx.x;
    if (i >= n4) return;
    const float* s = (blockIdx.z == 0) ? s0 : (blockIdx.z == 1) ? s1 : (blockIdx.z == 2) ? s2 : s3;
    float4 x = reinterpret_cast<const float4*>(s)[i];
    ushort4 o; o.x = f2bf(x.x); o.y = f2bf(x.y); o.z = f2bf(x.z); o.w = f2bf(x.w);
    reinterpret_cast<ushort4*>(dst + (size_t)blockIdx.z * n4 * 4)[i] = o;
}

// f32 [n][n] -> bf16 transposed [n][n], scaled; z selects src, dst contiguous
__global__ __launch_bounds__(256)
void twcast4(const float* __restrict__ s0, const float* __restrict__ s1,
             const float* __restrict__ s2, const float* __restrict__ s3,
             unsigned short* __restrict__ dstall, int n)
{
    __shared__ unsigned short t[64][72];
    const float* src = (blockIdx.z == 0) ? s0 : (blockIdx.z == 1) ? s1 : (blockIdx.z == 2) ? s2 : s3;
    const float scale = (blockIdx.z == 0) ? 0.125f : 1.0f;
    unsigned short* dst = dstall + (size_t)blockIdx.z * n * n;
    const int r0 = blockIdx.y * 64, c0 = blockIdx.x * 64;
    const int lrow = threadIdx.x >> 2, lseg = (threadIdx.x & 3) << 4;
    const float4* g4 = reinterpret_cast<const float4*>(src + (long)(r0 + lrow) * n + c0 + lseg);
    alignas(16) unsigned short tmp[16];
#pragma unroll
    for (int q = 0; q < 4; ++q) {
        float4 x = g4[q];
        tmp[4*q+0] = f2bf(x.x * scale); tmp[4*q+1] = f2bf(x.y * scale);
        tmp[4*q+2] = f2bf(x.z * scale); tmp[4*q+3] = f2bf(x.w * scale);
    }
#pragma unroll
    for (int j = 0; j < 16; ++j) t[lrow][lseg + j] = tmp[j];
    __syncthreads();
#pragma unroll
    for (int j = 0; j < 16; ++j) tmp[j] = t[lseg + j][lrow];
    unsigned short* d = dst + (long)(c0 + lrow) * n + r0 + lseg;
    *reinterpret_cast<u32x4*>(d)     = *reinterpret_cast<const u32x4*>(tmp);
    *reinterpret_cast<u32x4*>(d + 8) = *reinterpret_cast<const u32x4*>(tmp + 8);
}

// bq2[0][:] = wqb * 0.125, bq2[1][:] = wkb
__global__ __launch_bounds__(256)
void bias2(const float* __restrict__ a, const float* __restrict__ b, float* __restrict__ dst)
{
    const int i = blockIdx.x * 256 + threadIdx.x;
    if (i < DM) { dst[i] = a[i] * 0.125f; dst[DM + i] = b[i]; }
}

extern "C" void kernel_launch(void* const* d_in, const int* in_sizes, int n_in,
                              void* d_out, int out_size, void* d_ws, size_t ws_size,
                              hipStream_t stream)
{
    (void)in_sizes; (void)n_in; (void)out_size;
    const float* v_in = (const float*)d_in[0];
    const float* k_in = (const float*)d_in[1];
    const float* q_in = (const float*)d_in[2];
    const float* p_in = (const float*)d_in[3];
    const float* wq   = (const float*)d_in[4];
    const float* wqb  = (const float*)d_in[5];
    const float* wk   = (const float*)d_in[6];
    const float* wkb  = (const float*)d_in[7];
    const float* wvw  = (const float*)d_in[8];
    const float* wvb  = (const float*)d_in[9];
    const float* wc   = (const float*)d_in[10];
    const float* wcb  = (const float*)d_in[11];
    float* out = (float*)d_out;

    char* ws = (char*)d_ws;
    size_t off = 0;
    auto take = [&](size_t n) { char* p = ws + off; off += (n + 255) & ~(size_t)255; return p; };
    unsigned short* qbf = (unsigned short*)take((size_t)BS * DM * 2);  // qbf..pbf contiguous
    unsigned short* kbf = (unsigned short*)take((size_t)BS * DM * 2);
    unsigned short* vbf = (unsigned short*)take((size_t)BS * DM * 2);
    unsigned short* pbf = (unsigned short*)take((size_t)BS * DM * 2);
    unsigned short* wqT = (unsigned short*)take((size_t)DM * DM * 2);  // wqT..wcT contiguous
    unsigned short* wkT = (unsigned short*)take((size_t)DM * DM * 2);
    unsigned short* wvT = (unsigned short*)take((size_t)DM * DM * 2);
    unsigned short* wcT = (unsigned short*)take((size_t)DM * DM * 2);
    float*          bq2 = (float*)take((size_t)2 * DM * 4);
    unsigned short* qh  = (unsigned short*)take((size_t)BS * DM * 2);  // qh,kh contiguous
    unsigned short* kh  = (unsigned short*)take((size_t)BS * DM * 2);
    unsigned short* vhT = (unsigned short*)take((size_t)BS * DM * 2);
    unsigned short* ao  = (unsigned short*)take((size_t)BS * DM * 2);
    const size_t ssz = (size_t)NB * HSS * 2;
    unsigned short* B1 = (unsigned short*)take(ssz);
    unsigned short* B2 = (unsigned short*)take(ssz);
    unsigned short* B3 = (unsigned short*)take(ssz);
    const bool dual = (ws_size >= off + ssz);          // 4th S x S buffer fits?
    unsigned short* B4 = dual ? (unsigned short*)take(ssz) : nullptr;
    (void)kbf; (void)wkT;

    const int n4 = BS * DM / 4;
    const dim3 blk(256);

    cast4<<<dim3(n4 / 256, 1, 4), blk, 0, stream>>>(q_in, k_in, v_in, p_in, qbf, n4);
    twcast4<<<dim3(16, 16, 4), blk, 0, stream>>>(wq, wk, wvw, wc, wqT, DM);
    bias2<<<dim3(4), blk, 0, stream>>>(wqb, wkb, bq2);

    // q,k projections merged over z (alpha folded into wqT/bq2)
    gemmS<EPI_BFB,false,false,false,false><<<dim3(8, 16, 2), blk, 0, stream>>>(
        qbf, 0, (long)BS*DM, DM,  wqT, 0, (long)DM*DM, DM,  qh, nullptr, 0, (long)BS*DM, DM,
        bq2, DM, DM, DM);
    // vhT[b][dm][t] = (v@wv + b)^T
    gemmS<EPI_VTB,false,false,false,false><<<dim3(8, 8, 2), blk, 0, stream>>>(
        wvT, 0, 0, DM,  vbf, 0, SDM, DM,  vhT, nullptr, 0, (long)DM*S, S,
        wvb, 0, DM, S);

    unsigned short *sqkbuf, *ptbuf, *pbuf = B1, *lbuf;
    if (dual) {
        // P -> B1, P^T -> B2 in one pass
        gemmS<EPI_PACK2,false,false,true,false><<<dim3(8, 8, 32), blk, 0, stream>>>(
            qh, SDM, 64, DM,  pbf, SDM, 64, DM,  B1, B2, HSS, SS, S,  wvb, 0, 64, S);
        ptbuf = B2; sqkbuf = B3; lbuf = B4;
    } else {
        // packT[s][t] = elu(ph[s].qh[t])+1 -> B1
        gemmS<EPI_PACK,false,false,true,false><<<dim3(8, 8, 32), blk, 0, stream>>>(
            pbf, SDM, 64, DM,  qh, SDM, 64, DM,  B1, nullptr, HSS, SS, S,  wvb, 0, 64, S);
        ptbuf = B1; sqkbuf = B2; lbuf = B3;
    }
    // sQK[t][s] = (qh.kh) * tril/(t+1)
    gemmS<EPI_MASK,false,true,true,false><<<dim3(8, 8, 32), blk, 0, stream>>>(
        qh, SDM, 64, DM,  kh, SDM, 64, DM,  sqkbuf, nullptr, HSS, SS, S,  wvb, 0, 64, S);
    // unpack (logits) = sQK @ P  (B = P^T rows j), causal-K -> lbuf (bf16)
    gemmS<EPI_BF,true,false,true,false><<<dim3(8, 8, 32), blk, 0, stream>>>(
        sqkbuf, HSS, SS, S,  ptbuf, HSS, SS, S,  lbuf, nullptr, HSS, SS, S,  wvb, 0, S, S);
    // softmax: lbuf -> sqkbuf (sQK dead)
    softmax_rows<<<dim3(NB*H*S/4), blk, 0, stream>>>(lbuf, sqkbuf);
    if (!dual) {
        // pack[t][s] = elu(qh.ph)+1 -> B1 (packT dead)
        gemmS<EPI_PACK,false,false,true,false><<<dim3(8, 8, 32), blk, 0, stream>>>(
            qh, SDM, 64, DM,  pbf, SDM, 64, DM,  B1, nullptr, HSS, SS, S,  wvb, 0, 64, S);
    }
    // s2[t][s] = (sm . P[s,:]) * tril/(t+1)  (full K) -> lbuf (logits dead)
    gemmS<EPI_MASK,false,true,true,false><<<dim3(8, 8, 32), blk, 0, stream>>>(
        sqkbuf, HSS, SS, S,  pbuf, HSS, SS, S,  lbuf, nullptr, HSS, SS, S,  wvb, 0, S, S);
    // attn_out[t][d] = s2 @ vh (B = vhT head-slice [d][s], NV=64), causal-K
    gemmS<EPI_BF,true,false,false,true><<<dim3(1, 8, 32), blk, 0, stream>>>(
        lbuf, HSS, SS, S,  vhT, (long)DM*S, (long)64*S, S,  ao, nullptr, SDM, 64, DM,
        wvb, 0, S, 64);
    // out = ao @ wc + b (f32)
    gemmS<EPI_OUT,false,false,false,false><<<dim3(8, 16, 1), blk, 0, stream>>>(
        ao, 0, 0, DM,  wcT, 0, 0, DM,  out, nullptr, 0, 0, DM,  wcb, 0, DM, DM);
}